// Round 6
// baseline (226.008 us; speedup 1.0000x reference)
//
#include <hip/hip_runtime.h>

#define D 128
#define RS_STRIDE 64      // floats (256 B) between result slots

typedef __attribute__((ext_vector_type(8))) short bf16x8;
typedef __attribute__((ext_vector_type(8))) unsigned short u16x8;
typedef __attribute__((ext_vector_type(4))) float f32x4;

__device__ __forceinline__ unsigned short f2bf(float f) {
    unsigned u = __float_as_uint(f);
    unsigned r = (u + 0x7fffu + ((u >> 16) & 1u)) >> 16;
    return (unsigned short)r;
}
__device__ __forceinline__ float bf2f(unsigned short h) {
    return __uint_as_float(((unsigned)h) << 16);
}
__device__ __forceinline__ ushort4 pack4(float4 v) {
    ushort4 o; o.x = f2bf(v.x); o.y = f2bf(v.y); o.z = f2bf(v.z); o.w = f2bf(v.w);
    return o;
}

// -------------------------------------------------------------------------
// One prep pass: emb fp32->bf16, W/M fp32->bf16, zero strided rs slots and
// the done counter, build row_ptr[N+1] from sorted segment_ids.
__global__ void prep_kernel(const float* __restrict__ emb, const float* __restrict__ W,
                            const float* __restrict__ M, const int* __restrict__ seg,
                            unsigned short* __restrict__ embb, unsigned short* __restrict__ Wb,
                            unsigned short* __restrict__ Mb, float* __restrict__ rs,
                            int* __restrict__ row_ptr, int* __restrict__ done,
                            int n4, int E, int N) {
    int i = blockIdx.x * blockDim.x + threadIdx.x;
    if (i < n4) ((ushort4*)embb)[i] = pack4(((const float4*)emb)[i]);
    if (i < 4096)       ((ushort4*)Wb)[i]        = pack4(((const float4*)W)[i]);
    else if (i < 8192)  ((ushort4*)Mb)[i - 4096] = pack4(((const float4*)M)[i - 4096]);
    if (i < D) rs[i * RS_STRIDE] = 0.0f;
    if (i == D) *done = 0;
    if (i < E) {
        int s = seg[i];
        if (i == 0) {
            for (int n = 0; n <= s; ++n) row_ptr[n] = 0;
        } else {
            int sp = seg[i - 1];
            for (int n = sp + 1; n <= s; ++n) row_ptr[n] = i;
        }
        if (i == E - 1) {
            for (int n = s + 1; n <= N; ++n) row_ptr[n] = E;
        }
    }
}

// -------------------------------------------------------------------------
// Fused agg + MFMA matvec + relu/sum + (last block) softmax.
// Block = 16 nodes, 4 waves. LDS xs/as hold bf16 x and aggregate rows in
// u16x8 chunks, XOR-swizzled (chunk ^ node) so the MFMA-fragment ds_read_b128
// pattern (16 lanes/quad hitting one bank group unswizzled) becomes 2-way.
__global__ __launch_bounds__(256) void fused_kernel(
    const int* __restrict__ node_ids, const int* __restrict__ nbr,
    const int* __restrict__ row_ptr, const unsigned short* __restrict__ embb,
    const unsigned short* __restrict__ Wb, const unsigned short* __restrict__ Mb,
    float* __restrict__ rs, int* __restrict__ done, float* __restrict__ out,
    int N, int nblocks) {
    __shared__ u16x8 xs4[256];   // [node 0..15][chunk 0..15], swizzled
    __shared__ u16x8 as4[256];
    __shared__ int amlast;

    int t = threadIdx.x;
    int wave = t >> 6, tt = t & 63;
    int nb = blockIdx.x << 4;

    int ns  = tt >> 4;               // node sub within wave, 0..3
    int n15 = (wave << 2) + ns;      // node index within block, 0..15
    int n   = nb + n15;
    bool nvalid = n < N;

    // ---- x gather (1 load/lane): node n15, chunk c2 ----
    int c2 = tt & 15;
    const u16x8 z8 = {0, 0, 0, 0, 0, 0, 0, 0};
    u16x8 xv = z8;
    if (nvalid) {
        int nid = node_ids[n];
        xv = *((const u16x8*)(embb + (size_t)nid * D) + c2);
    }

    // ---- aggregate phase: 4 edge streams (jj) x 4 chunk-lanes (cc) / node ----
    int jj = (tt >> 2) & 3;
    int cc = tt & 3;                 // owns chunks cc, cc+4, cc+8, cc+12
    int lo = 0, hi = 0;
    if (nvalid) { lo = row_ptr[n]; hi = row_ptr[n + 1]; }

    float s[4][8];
#pragma unroll
    for (int q = 0; q < 4; ++q)
#pragma unroll
        for (int k = 0; k < 8; ++k) s[q][k] = 0.f;

    int e = lo + jj;
    int id = (e < hi) ? nbr[e] : -1;
    while (id >= 0) {
        const u16x8* r = (const u16x8*)(embb + (size_t)id * D);
        int e2 = e + 4;
        int id2 = (e2 < hi) ? nbr[e2] : -1;   // prefetch next id
        u16x8 v0 = r[cc], v1 = r[cc + 4], v2 = r[cc + 8], v3 = r[cc + 12];
#pragma unroll
        for (int k = 0; k < 8; ++k) {
            s[0][k] += bf2f((unsigned short)v0[k]);
            s[1][k] += bf2f((unsigned short)v1[k]);
            s[2][k] += bf2f((unsigned short)v2[k]);
            s[3][k] += bf2f((unsigned short)v3[k]);
        }
        e = e2; id = id2;
    }
    // fold the 4 streams (lane bits 2,3)
#pragma unroll
    for (int q = 0; q < 4; ++q)
#pragma unroll
        for (int k = 0; k < 8; ++k) {
            float x = s[q][k];
            x += __shfl_xor(x, 4);
            x += __shfl_xor(x, 8);
            s[q][k] = x;
        }

    xs4[(n15 << 4) + (c2 ^ n15)] = xv;
    if (jj == 0) {
#pragma unroll
        for (int q = 0; q < 4; ++q) {
            int chunk = cc + (q << 2);
            u16x8 ov;
#pragma unroll
            for (int k = 0; k < 8; ++k) ov[k] = f2bf(s[q][k]);
            as4[(n15 << 4) + (chunk ^ n15)] = ov;
        }
    }
    __syncthreads();

    // ---- MFMA matvec phase: wave handles dim-tiles 2*wave, 2*wave+1 ----
    // A-frag: A[m=lane&15][k=quad*8+j] -> LDS chunk quad+4ks of node col.
    // B-frag: B[k=quad*8+j][n=lane&15] = W[dim][k].  C/D: col=dim, row=node.
    int quad = tt >> 4, col = tt & 15;
#pragma unroll
    for (int s2 = 0; s2 < 2; ++s2) {
        int dt = (wave << 1) + s2;
        const unsigned short* wr = Wb + ((dt * 16 + col) * D + quad * 8);
        const unsigned short* mr = Mb + ((dt * 16 + col) * D + quad * 8);
        f32x4 acc = {0.f, 0.f, 0.f, 0.f};
#pragma unroll
        for (int ks = 0; ks < 4; ++ks) {
            bf16x8 bw = *(const bf16x8*)(wr + ks * 32);
            bf16x8 bm = *(const bf16x8*)(mr + ks * 32);
            int p = (col << 4) + ((quad + (ks << 2)) ^ col);
            bf16x8 ax = *(const bf16x8*)&xs4[p];
            bf16x8 aa = *(const bf16x8*)&as4[p];
            acc = __builtin_amdgcn_mfma_f32_16x16x32_bf16(ax, bw, acc, 0, 0, 0);
            acc = __builtin_amdgcn_mfma_f32_16x16x32_bf16(aa, bm, acc, 0, 0, 0);
        }
        float v = fmaxf(acc[0], 0.f) + fmaxf(acc[1], 0.f)
                + fmaxf(acc[2], 0.f) + fmaxf(acc[3], 0.f);
        v += __shfl_xor(v, 16);
        v += __shfl_xor(v, 32);
        if (tt < 16) atomicAdd(&rs[(dt * 16 + col) * RS_STRIDE], v);
    }

    // ---- last block finalizes softmax ----
    __threadfence();
    if (t == 0) amlast = (atomicAdd(done, 1) == nblocks - 1);
    __syncthreads();
    if (amlast) {
        __threadfence();
        if (t < 64) {
            float v0 = __hip_atomic_load(&rs[t * RS_STRIDE],
                                         __ATOMIC_RELAXED, __HIP_MEMORY_SCOPE_AGENT);
            float v1 = __hip_atomic_load(&rs[(t + 64) * RS_STRIDE],
                                         __ATOMIC_RELAXED, __HIP_MEMORY_SCOPE_AGENT);
            float m = fmaxf(v0, v1);
            for (int o = 32; o > 0; o >>= 1) m = fmaxf(m, __shfl_xor(m, o));
            float e0 = expf(v0 - m);
            float e1 = expf(v1 - m);
            float su = e0 + e1;
            for (int o = 32; o > 0; o >>= 1) su += __shfl_xor(su, o);
            float inv = 1.0f / su;
            out[t] = e0 * inv;
            out[t + 64] = e1 * inv;
        }
    }
}

extern "C" void kernel_launch(void* const* d_in, const int* in_sizes, int n_in,
                              void* d_out, int out_size, void* d_ws, size_t ws_size,
                              hipStream_t stream) {
    const int*   node_ids = (const int*)d_in[0];
    const int*   nbr      = (const int*)d_in[1];
    const int*   seg      = (const int*)d_in[2];
    const float* W        = (const float*)d_in[3];
    const float* M        = (const float*)d_in[4];
    const float* emb      = (const float*)d_in[5];
    float* out = (float*)d_out;

    int N = in_sizes[0];
    int E = in_sizes[1];
    long long VD = in_sizes[5];          // V*D elements
    int nblocks = (N + 15) / 16;

    // ws layout: embb[V*D] u16 | Wb | Mb | rs fp32 | row_ptr int[N+1] | done
    unsigned short* embb = (unsigned short*)d_ws;
    unsigned short* Wb   = embb + (size_t)VD;
    unsigned short* Mb   = Wb + D * D;
    float* rs            = (float*)(Mb + D * D);
    int* row_ptr         = (int*)(rs + (size_t)D * RS_STRIDE);
    int* done            = row_ptr + (N + 1);

    int n4 = (int)(VD / 4);
    int prep_n = n4;
    if (prep_n < E) prep_n = E;
    if (prep_n < 8192) prep_n = 8192;

    prep_kernel<<<(prep_n + 255) / 256, 256, 0, stream>>>(emb, W, M, seg, embb, Wb, Mb,
                                                          rs, row_ptr, done, n4, E, N);
    fused_kernel<<<nblocks, 256, 0, stream>>>(node_ids, nbr, row_ptr, embb, Wb, Mb,
                                              rs, done, out, N, nblocks);
}

// Round 7
// 159.733 us; speedup vs baseline: 1.4149x; 1.4149x over previous
//
#include <hip/hip_runtime.h>

#define D 128
#define RS_STRIDE 64      // floats (256 B) between result slots

typedef __attribute__((ext_vector_type(8))) short bf16x8;
typedef __attribute__((ext_vector_type(8))) unsigned short u16x8;
typedef __attribute__((ext_vector_type(16))) char i8x16;
typedef __attribute__((ext_vector_type(4))) float f32x4;

__device__ __forceinline__ unsigned short f2bf(float f) {
    unsigned u = __float_as_uint(f);
    unsigned r = (u + 0x7fffu + ((u >> 16) & 1u)) >> 16;
    return (unsigned short)r;
}
__device__ __forceinline__ ushort4 pack4(float4 v) {
    ushort4 o; o.x = f2bf(v.x); o.y = f2bf(v.y); o.z = f2bf(v.z); o.w = f2bf(v.w);
    return o;
}

// -------------------------------------------------------------------------
// Prep: emb fp32 -> int8 per-row-scaled (4 rows/block, 64 lanes/row, shfl row
// max), W/M -> bf16, zero strided rs slots, row_ptr[N+1] from sorted seg.
__global__ void prep_kernel(const float* __restrict__ emb, const float* __restrict__ W,
                            const float* __restrict__ M, const int* __restrict__ seg,
                            signed char* __restrict__ q8, float* __restrict__ scale,
                            unsigned short* __restrict__ Wb, unsigned short* __restrict__ Mb,
                            float* __restrict__ rs, int* __restrict__ row_ptr,
                            int V, int E, int N) {
    int t = threadIdx.x;
    int gtid = blockIdx.x * 256 + t;

    // per-row int8 quantization
    int r = blockIdx.x * 4 + (t >> 6);
    if (r < V) {
        int l = t & 63;
        float2 v = *(const float2*)(emb + (size_t)r * D + 2 * l);
        float m = fmaxf(fabsf(v.x), fabsf(v.y));
        for (int o = 1; o < 64; o <<= 1) m = fmaxf(m, __shfl_xor(m, o));
        float inv = (m > 0.f) ? 127.0f / m : 0.f;
        int qa = __float2int_rn(v.x * inv);
        int qb = __float2int_rn(v.y * inv);
        qa = min(max(qa, -127), 127);
        qb = min(max(qb, -127), 127);
        unsigned short pq = (unsigned short)(((unsigned char)qb << 8) | (unsigned char)qa);
        *(unsigned short*)(q8 + (size_t)r * D + 2 * l) = pq;
        if (l == 0) scale[r] = m * (1.0f / 127.0f);
    }

    if (gtid < 4096)      ((ushort4*)Wb)[gtid]        = pack4(((const float4*)W)[gtid]);
    else if (gtid < 8192) ((ushort4*)Mb)[gtid - 4096] = pack4(((const float4*)M)[gtid - 4096]);
    if (gtid < D) rs[gtid * RS_STRIDE] = 0.0f;

    if (gtid < E) {
        int s = seg[gtid];
        if (gtid == 0) {
            for (int n = 0; n <= s; ++n) row_ptr[n] = 0;
        } else {
            int sp = seg[gtid - 1];
            for (int n = sp + 1; n <= s; ++n) row_ptr[n] = gtid;
        }
        if (gtid == E - 1) {
            for (int n = s + 1; n <= N; ++n) row_ptr[n] = E;
        }
    }
}

// -------------------------------------------------------------------------
// Segment-sum of int8-scaled emb rows -> bf16 aggb. Wave = 1 node:
// 16 edge streams (j) x 4 chunk-lanes (cc, 32 dims each); next-id prefetch.
// fp32 accumulate via fma(q, row_scale, acc).
__global__ void agg_kernel(const int* __restrict__ nbr, const int* __restrict__ row_ptr,
                           const signed char* __restrict__ q8, const float* __restrict__ scale,
                           unsigned short* __restrict__ aggb, int N) {
    int n = blockIdx.x * 4 + (threadIdx.x >> 6);
    if (n >= N) return;
    int tt = threadIdx.x & 63;
    int cc = tt & 3;      // 32-dim chunk
    int j  = tt >> 2;     // edge stream 0..15

    int lo = row_ptr[n], hi = row_ptr[n + 1];

    float s[32];
#pragma unroll
    for (int k = 0; k < 32; ++k) s[k] = 0.f;

    int e = lo + j;
    int id = (e < hi) ? nbr[e] : -1;
    while (id >= 0) {
        const i8x16* r = (const i8x16*)(q8 + (size_t)id * D) + cc * 2;
        float sc = scale[id];
        int e2 = e + 16;
        int id2 = (e2 < hi) ? nbr[e2] : -1;   // prefetch next id
        i8x16 p0 = r[0], p1 = r[1];
#pragma unroll
        for (int k = 0; k < 16; ++k) {
            s[k]      = fmaf((float)p0[k], sc, s[k]);
            s[k + 16] = fmaf((float)p1[k], sc, s[k + 16]);
        }
        e = e2; id = id2;
    }
    // fold 16 streams (lane bits 2..5)
#pragma unroll
    for (int k = 0; k < 32; ++k) {
        float x = s[k];
        x += __shfl_xor(x, 4);
        x += __shfl_xor(x, 8);
        x += __shfl_xor(x, 16);
        x += __shfl_xor(x, 32);
        s[k] = x;
    }

    if (j == 0) {
        u16x8* o = (u16x8*)(aggb + (size_t)n * D) + cc * 4;
#pragma unroll
        for (int q = 0; q < 4; ++q) {
            u16x8 ov;
#pragma unroll
            for (int k = 0; k < 8; ++k) ov[k] = f2bf(s[q * 8 + k]);
            o[q] = ov;
        }
    }
}

// -------------------------------------------------------------------------
// MFMA matvec + relu + column-sum. Wave job = (dim-tile dt, node stripe);
// each wave handles 2 16-node groups. X gathered from fp32 emb via node_ids
// with in-register bf16 pack; aggregate from bf16 aggb.
// A-frag: A[m=lane&15][k=quad*8+j]; B-frag: B[k=quad*8+j][n=lane&15] = W[n][k]
// C/D: col=lane&15 (dim), row=quad*4+reg (node).
__global__ __launch_bounds__(256) void matvec_kernel(
    const int* __restrict__ node_ids, const float* __restrict__ emb,
    const unsigned short* __restrict__ aggb,
    const unsigned short* __restrict__ Wb, const unsigned short* __restrict__ Mb,
    float* __restrict__ rs, int N, int ngroups, int nstripes) {
    int t = threadIdx.x;
    int wid = blockIdx.x * 4 + (t >> 6);
    int l = t & 63;
    int quad = l >> 4, col = l & 15;
    int dt = wid & 7;
    int stripe = wid >> 3;

    bf16x8 bw[4], bm[4];
    int wrow = (dt * 16 + col) * D;
#pragma unroll
    for (int ks = 0; ks < 4; ++ks) {
        int off = wrow + ks * 32 + quad * 8;
        bw[ks] = *(const bf16x8*)(Wb + off);
        bm[ks] = *(const bf16x8*)(Mb + off);
    }

    const bf16x8 zero8 = {0, 0, 0, 0, 0, 0, 0, 0};
    float vsum = 0.f;

    for (int grp = stripe; grp < ngroups; grp += nstripes) {
        int node = grp * 16 + col;
        bool valid = node < N;
        int nid = valid ? node_ids[node] : 0;
        const unsigned short* ar = aggb + (size_t)node * D + quad * 8;

        f32x4 acc = {0.f, 0.f, 0.f, 0.f};
#pragma unroll
        for (int ks = 0; ks < 4; ++ks) {
            bf16x8 ax;
            if (valid) {
                const float4* xf = (const float4*)(emb + (size_t)nid * D + quad * 8 + ks * 32);
                ushort4 p0 = pack4(xf[0]);
                ushort4 p1 = pack4(xf[1]);
                ax[0] = (short)p0.x; ax[1] = (short)p0.y;
                ax[2] = (short)p0.z; ax[3] = (short)p0.w;
                ax[4] = (short)p1.x; ax[5] = (short)p1.y;
                ax[6] = (short)p1.z; ax[7] = (short)p1.w;
            } else ax = zero8;
            bf16x8 aa = valid ? *(const bf16x8*)(ar + ks * 32) : zero8;
            acc = __builtin_amdgcn_mfma_f32_16x16x32_bf16(ax, bw[ks], acc, 0, 0, 0);
            acc = __builtin_amdgcn_mfma_f32_16x16x32_bf16(aa, bm[ks], acc, 0, 0, 0);
        }
        vsum += fmaxf(acc[0], 0.f) + fmaxf(acc[1], 0.f)
              + fmaxf(acc[2], 0.f) + fmaxf(acc[3], 0.f);
    }

    vsum += __shfl_xor(vsum, 16);
    vsum += __shfl_xor(vsum, 32);
    if (l < 16) atomicAdd(&rs[(dt * 16 + col) * RS_STRIDE], vsum);
}

// -------------------------------------------------------------------------
__global__ void softmax_kernel(const float* __restrict__ rs, float* __restrict__ out) {
    int t = threadIdx.x;                 // 0..63
    float v0 = rs[t * RS_STRIDE];
    float v1 = rs[(t + 64) * RS_STRIDE];
    float m = fmaxf(v0, v1);
    for (int o = 32; o > 0; o >>= 1) m = fmaxf(m, __shfl_xor(m, o));
    float e0 = expf(v0 - m);
    float e1 = expf(v1 - m);
    float s = e0 + e1;
    for (int o = 32; o > 0; o >>= 1) s += __shfl_xor(s, o);
    float inv = 1.0f / s;
    out[t] = e0 * inv;
    out[t + 64] = e1 * inv;
}

extern "C" void kernel_launch(void* const* d_in, const int* in_sizes, int n_in,
                              void* d_out, int out_size, void* d_ws, size_t ws_size,
                              hipStream_t stream) {
    const int*   node_ids = (const int*)d_in[0];
    const int*   nbr      = (const int*)d_in[1];
    const int*   seg      = (const int*)d_in[2];
    const float* W        = (const float*)d_in[3];
    const float* M        = (const float*)d_in[4];
    const float* emb      = (const float*)d_in[5];
    float* out = (float*)d_out;

    int N = in_sizes[0];
    int E = in_sizes[1];
    long long VD = in_sizes[5];          // V*D elements
    int V = (int)(VD / D);
    int ngroups  = (N + 15) / 16;
    int nstripes = (ngroups + 1) / 2;    // each wave: exactly 2 groups
    int mv_blocks = 2 * nstripes;

    // ws layout: q8[V*D] i8 | scale[V] f32 | Wb | Mb u16 | aggb[N*D] u16 |
    //            rs fp32 | row_ptr int[N+1]   (~18.5 MB of 256 MiB)
    signed char* q8      = (signed char*)d_ws;
    float* scale         = (float*)(q8 + (size_t)V * D);
    unsigned short* Wb   = (unsigned short*)(scale + V);
    unsigned short* Mb   = Wb + D * D;
    unsigned short* aggb = Mb + D * D;
    float* rs            = (float*)(aggb + (size_t)N * D);
    int* row_ptr         = (int*)(rs + (size_t)D * RS_STRIDE);

    int prep_blocks = (V + 3) / 4;                  // row-quant coverage
    int min_blocks  = (E + 255) / 256;              // row_ptr coverage
    if (prep_blocks < min_blocks) prep_blocks = min_blocks;
    if (prep_blocks < 32) prep_blocks = 32;

    prep_kernel<<<prep_blocks, 256, 0, stream>>>(emb, W, M, seg, q8, scale, Wb, Mb,
                                                 rs, row_ptr, V, E, N);
    agg_kernel<<<(N + 3) / 4, 256, 0, stream>>>(nbr, row_ptr, q8, scale, aggb, N);
    matvec_kernel<<<mv_blocks, 256, 0, stream>>>(node_ids, emb, aggb, Wb, Mb,
                                                 rs, N, ngroups, nstripes);
    softmax_kernel<<<1, 64, 0, stream>>>(rs, out);
}